// Round 2
// baseline (541.445 us; speedup 1.0000x reference)
//
#include <hip/hip_runtime.h>

typedef __attribute__((ext_vector_type(8))) short short8;
typedef __attribute__((ext_vector_type(4))) unsigned short ushort4v;
typedef __attribute__((ext_vector_type(4))) float f32x4;
typedef __attribute__((ext_vector_type(4))) unsigned int uint4v;

#define SCALE_F 0.17677669529663687f  // 1/sqrt(32)
// swizzle: uses both token-col (t&7) and token-row (t>>3) bits so both
// phase-1 writes (lanes share col, differ row) and frag reads spread banks
#define SW(t) ((((t) ^ ((t) >> 3)) & 7) << 4)

__device__ __forceinline__ unsigned short f2bf(float f){
  unsigned u = __builtin_bit_cast(unsigned, f);
  u += 0x7fffu + ((u >> 16) & 1u);          // RNE
  return (unsigned short)(u >> 16);
}
__device__ __forceinline__ float bf2f(unsigned short h){
  unsigned u = ((unsigned)h) << 16;
  return __builtin_bit_cast(float, u);
}
// HW packed f32->bf16 (RNE): dst = bf(a)|bf(b)<<16
__device__ __forceinline__ unsigned cvtpk(float a, float b){
  unsigned w;
  asm("v_cvt_pk_bf16_f32 %0, %1, %2" : "=v"(w) : "v"(a), "v"(b));
  return w;
}
__device__ __forceinline__ void st_pk4(void* p, f32x4 a){
  uint2 u; u.x = cvtpk(a[0], a[1]); u.y = cvtpk(a[2], a[3]);
  *(uint2*)p = u;
}

// ---------------------------------------------------------------------------
// LDS map (39424 B -> 4 blocks/CU):
//   [    0,16384) : x window bf16 [t=64][c=128] stride 256B, swz SW(t)
//                   (reused as attn-out [t][c] after last head's GEMM)
//   [16384,21504) : q_h bf16 [t=64][c=32] stride 80B (pad; no xor)
//   [21504,26624) : k_h bf16 [t=64][c=32] stride 80B
//   [26624,31232) : vT_h bf16 [c=32][t=64] stride 144B
//   [31232,39424) : S/P bf16 [64][64] stride 128B, swz SW(row), in-place
// ---------------------------------------------------------------------------

template<bool WSB>
__global__ void __launch_bounds__(256, 4)
swin_fused(const float* __restrict__ x, const float* __restrict__ qkvw_f,
           const float* __restrict__ projw_f, const float* __restrict__ projb,
           const float* __restrict__ btab, const unsigned short* __restrict__ wbf,
           float* __restrict__ out)
{
  __shared__ __align__(16) unsigned char sm[39424];
  unsigned char* const smq = sm + 16384;
  unsigned char* const smk = sm + 21504;
  unsigned char* const smv = sm + 26624;
  unsigned char* const smS = sm + 31232;

  const int tid  = threadIdx.x;
  const int lane = tid & 63, wv = tid >> 6;
  const int lr = lane & 15, lg = lane >> 4;

  // XCD-aware swizzle: 8192 blocks, 8 XCDs -> each XCD one batch plane
  const int bid = blockIdx.x;
  const int sw  = ((bid & 7) << 10) | (bid >> 3);
  const int b   = sw >> 10;
  const int wh  = (sw >> 5) & 31, ww = sw & 31;
  const int hb  = wh * 8 + 4, wb = ww * 8 + 4;   // roll(-4): shifted -> source
  const bool h31 = (wh == 31), w31 = (ww == 31);

  // ---- Phase 1: load x window (float4) -> bf16 LDS [t][c] swizzled ----
  {
    #pragma unroll
    for (int it = 0; it < 8; ++it) {
      const int f = tid + 256 * it;          // 0..2047 float4-units
      const int c    = f >> 4;               // channel
      const int rr   = (f >> 1) & 7;         // window row
      const int half = f & 1;                // which float4 of the row
      const int gh = (hb + rr) & 255;
      const int gw = (wb + 4 * half) & 255;  // 16B aligned, no intra-wrap
      const f32x4 v = *(const f32x4*)(x + (((b * 128 + c) << 16) + (gh << 8) + gw));
      const int t0 = rr * 8 + 4 * half;
      #pragma unroll
      for (int e = 0; e < 4; ++e) {
        const int t = t0 + e;
        *(unsigned short*)(sm + t * 256 + ((2 * c) ^ SW(t))) = f2bf(v[e]);
      }
    }
  }
  __syncthreads();

  // Per-thread constants for attention epilogues
  const int ktc = wv * 16 + lr;              // key column owned in QK
  const int ki = ktc >> 3, kj = ktc & 7;
  int boff[4][4];
  #pragma unroll
  for (int mt = 0; mt < 4; ++mt)
    #pragma unroll
    for (int r = 0; r < 4; ++r) {
      const int qrow = mt * 16 + 4 * lg + r;
      boff[mt][r] = (((qrow >> 3) - ki + 7) * 15 + ((qrow & 7) - kj + 7)) * 4;
    }

  f32x4 accpv[8];
  #pragma unroll
  for (int z = 0; z < 8; ++z) accpv[z] = (f32x4)(0.f);

  // x B-fragment loader
  auto ldx = [&](int t, int kk) -> short8 {
    return *(const short8*)(sm + t * 256 + ((64 * kk + 16 * lg) ^ SW(t)));
  };
  // weight A-fragment loader (row of [384|128]x128 matrix, K-block kk)
  auto ldw8 = [&](const float* wf, const unsigned short* wb16, int row, int kk) -> short8 {
    const int off = row * 128 + kk * 32 + 8 * lg;
    if constexpr (WSB) {
      return *(const short8*)(wb16 + off);
    } else {
      const float* p = wf + off;
      short8 r;
      #pragma unroll
      for (int e = 0; e < 8; ++e) r[e] = (short)f2bf(p[e]);
      return r;
    }
  };

  #pragma unroll 1
  for (int h = 0; h < 4; ++h) {
    // ---- per-head QKV sub-GEMM ----
    {
      // primary M-tile: wv 0,1 -> q halves; wv 2,3 -> k halves
      const int prow0 = ((wv < 2) ? 32 * h : 128 + 32 * h) + 16 * (wv & 1);
      short8 Af[4];
      #pragma unroll
      for (int kk = 0; kk < 4; ++kk) Af[kk] = ldw8(qkvw_f, wbf, prow0 + lr, kk);
      unsigned char* const dst = (wv < 2) ? smq : smk;
      #pragma unroll
      for (int nt = 0; nt < 4; ++nt) {
        const int t = nt * 16 + lr;
        f32x4 acc = (f32x4)(0.f);
        #pragma unroll
        for (int kk = 0; kk < 4; ++kk)
          acc = __builtin_amdgcn_mfma_f32_16x16x32_bf16(Af[kk], ldx(t, kk), acc, 0, 0, 0);
        if (wv < 2) { acc[0] *= SCALE_F; acc[1] *= SCALE_F; acc[2] *= SCALE_F; acc[3] *= SCALE_F; }
        st_pk4(dst + t * 80 + 32 * (wv & 1) + 8 * lg, acc);
      }
      // v M-tile: rows 256+32h+16*(wv>>1), N-half (wv&1)
      const int vrow0 = 256 + 32 * h + 16 * (wv >> 1);
      short8 Av[4];
      #pragma unroll
      for (int kk = 0; kk < 4; ++kk) Av[kk] = ldw8(qkvw_f, wbf, vrow0 + lr, kk);
      #pragma unroll
      for (int ntl = 0; ntl < 2; ++ntl) {
        const int t = (2 * (wv & 1) + ntl) * 16 + lr;
        f32x4 acc = (f32x4)(0.f);
        #pragma unroll
        for (int kk = 0; kk < 4; ++kk)
          acc = __builtin_amdgcn_mfma_f32_16x16x32_bf16(Av[kk], ldx(t, kk), acc, 0, 0, 0);
        const int cb = 16 * (wv >> 1) + 4 * lg;
        #pragma unroll
        for (int r = 0; r < 4; ++r)
          *(unsigned short*)(smv + (cb + r) * 144 + 2 * t) = f2bf(acc[r]);
      }
    }
    __syncthreads();

    // ---- QK^T (+bias +mask) -> S ----
    {
      const short8 kb = *(const short8*)(smk + ktc * 80 + 16 * lg);
      #pragma unroll
      for (int mt = 0; mt < 4; ++mt) {
        const short8 qa = *(const short8*)(smq + (mt * 16 + lr) * 80 + 16 * lg);
        const f32x4 s = __builtin_amdgcn_mfma_f32_16x16x32_bf16(qa, kb, (f32x4)(0.f), 0, 0, 0);
        #pragma unroll
        for (int r = 0; r < 4; ++r) {
          const int qrow = mt * 16 + 4 * lg + r;
          float val = s[r] + btab[boff[mt][r] + h];
          if (h31 | w31) {                     // wave-uniform branch
            const int qi = qrow >> 3, qj = qrow & 7;
            const bool bad = (h31 && ((qi >= 4) != (ki >= 4))) ||
                             (w31 && ((qj >= 4) != (kj >= 4)));
            val += bad ? -100.f : 0.f;
          }
          *(unsigned short*)(smS + qrow * 128 + ((2 * ktc) ^ SW(qrow))) = f2bf(val);
        }
      }
    }
    __syncthreads();

    // ---- softmax: 4 lanes/row, in-place S->P ----
    {
      const int srow = tid >> 2, sq = tid & 3;
      unsigned char* const rp = smS + srow * 128;
      const int o0 = (32 * sq) ^ SW(srow);
      const int o1 = (32 * sq + 16) ^ SW(srow);
      const short8 s0 = *(const short8*)(rp + o0);
      const short8 s1 = *(const short8*)(rp + o1);
      float v[16];
      #pragma unroll
      for (int e = 0; e < 8; ++e) { v[e] = bf2f((unsigned short)s0[e]); v[e + 8] = bf2f((unsigned short)s1[e]); }
      float mx = v[0];
      #pragma unroll
      for (int e = 1; e < 16; ++e) mx = fmaxf(mx, v[e]);
      mx = fmaxf(mx, __shfl_xor(mx, 1));
      mx = fmaxf(mx, __shfl_xor(mx, 2));
      float sum = 0.f;
      #pragma unroll
      for (int e = 0; e < 16; ++e) { v[e] = __expf(v[e] - mx); sum += v[e]; }
      sum += __shfl_xor(sum, 1);
      sum += __shfl_xor(sum, 2);
      const float inv = 1.f / sum;
      uint4v w0, w1;
      w0.x = cvtpk(v[0] * inv, v[1] * inv);  w0.y = cvtpk(v[2] * inv, v[3] * inv);
      w0.z = cvtpk(v[4] * inv, v[5] * inv);  w0.w = cvtpk(v[6] * inv, v[7] * inv);
      w1.x = cvtpk(v[8] * inv, v[9] * inv);  w1.y = cvtpk(v[10] * inv, v[11] * inv);
      w1.z = cvtpk(v[12] * inv, v[13] * inv); w1.w = cvtpk(v[14] * inv, v[15] * inv);
      *(uint4v*)(rp + o0) = w0;
      *(uint4v*)(rp + o1) = w1;
    }
    __syncthreads();

    // ---- PV: wave owns q rows [16wv,16wv+16); accumulate over heads ----
    {
      const int q = wv * 16 + lr;
      const short8 pa0 = *(const short8*)(smS + q * 128 + ((16 * lg) ^ SW(q)));
      const short8 pa1 = *(const short8*)(smS + q * 128 + ((64 + 16 * lg) ^ SW(q)));
      #pragma unroll
      for (int nd = 0; nd < 2; ++nd) {
        const int c = nd * 16 + lr;
        const short8 vb0 = *(const short8*)(smv + c * 144 + 16 * lg);
        const short8 vb1 = *(const short8*)(smv + c * 144 + 64 + 16 * lg);
        f32x4 a = accpv[2 * h + nd];
        a = __builtin_amdgcn_mfma_f32_16x16x32_bf16(pa0, vb0, a, 0, 0, 0);
        a = __builtin_amdgcn_mfma_f32_16x16x32_bf16(pa1, vb1, a, 0, 0, 0);
        accpv[2 * h + nd] = a;
      }
    }
    __syncthreads();   // protect q/k/vT/S for next head's GEMM epilogue
  }

  // ---- attn-out -> LDS x region (x fully consumed) ----
  {
    #pragma unroll
    for (int h = 0; h < 4; ++h)
      #pragma unroll
      for (int nd = 0; nd < 2; ++nd) {
        const int c = 32 * h + nd * 16 + lr;
        const f32x4 a = accpv[2 * h + nd];
        #pragma unroll
        for (int r = 0; r < 4; ++r) {
          const int t = wv * 16 + 4 * lg + r;
          *(unsigned short*)(sm + t * 256 + ((2 * c) ^ SW(t))) = f2bf(a[r]);
        }
      }
  }
  __syncthreads();

  // ---- proj (D[t][o]) + bias + store with roll(+4,+4) ----
  {
    short8 Aa[16];
    #pragma unroll
    for (int mt = 0; mt < 4; ++mt)
      #pragma unroll
      for (int kk = 0; kk < 4; ++kk) {
        const int t = mt * 16 + lr;
        Aa[mt * 4 + kk] = *(const short8*)(sm + t * 256 + ((64 * kk + 16 * lg) ^ SW(t)));
      }
    #pragma unroll
    for (int ntl = 0; ntl < 2; ++ntl) {
      const int o = (wv + 4 * ntl) * 16 + lr;
      short8 Bw[4];
      #pragma unroll
      for (int kk = 0; kk < 4; ++kk) {
        const int off = o * 128 + kk * 32 + 8 * lg;
        if constexpr (WSB) {
          Bw[kk] = *(const short8*)(wbf + 49152 + off);
        } else {
          const float* p = projw_f + off;
          short8 r;
          #pragma unroll
          for (int e = 0; e < 8; ++e) r[e] = (short)f2bf(p[e]);
          Bw[kk] = r;
        }
      }
      const float pb = projb[o];
      #pragma unroll
      for (int mt = 0; mt < 4; ++mt) {
        f32x4 acc = (f32x4)(0.f);
        #pragma unroll
        for (int kk = 0; kk < 4; ++kk)
          acc = __builtin_amdgcn_mfma_f32_16x16x32_bf16(Aa[mt * 4 + kk], Bw[kk], acc, 0, 0, 0);
        const int t0 = mt * 16 + 4 * lg;       // 4 consecutive tokens, same row
        const int gh = (hb + (t0 >> 3)) & 255;
        const int gw0 = (wb + (t0 & 7)) & 255; // mult of 4 -> aligned, no wrap
        f32x4 ov;
        ov[0] = acc[0] + pb; ov[1] = acc[1] + pb; ov[2] = acc[2] + pb; ov[3] = acc[3] + pb;
        *(f32x4*)(out + (((b * 128 + o) << 16) + (gh << 8) + gw0)) = ov;
      }
    }
  }
}

// One-time (per launch) weight fp32 -> bf16 into workspace.
__global__ void prep_weights(const float* __restrict__ qw, const float* __restrict__ pw,
                             unsigned short* __restrict__ wsb)
{
  const int i = blockIdx.x * 256 + threadIdx.x;
  const int idx = i * 4;                        // 65536 elements total
  const float* src = (idx < 49152) ? (qw + idx) : (pw + (idx - 49152));
  f32x4 v = *(const f32x4*)src;
  ushort4v o;
  #pragma unroll
  for (int e = 0; e < 4; ++e) o[e] = f2bf(v[e]);
  *(ushort4v*)(wsb + idx) = o;
}

extern "C" void kernel_launch(void* const* d_in, const int* in_sizes, int n_in,
                              void* d_out, int out_size, void* d_ws, size_t ws_size,
                              hipStream_t stream) {
  const float* x     = (const float*)d_in[0];
  const float* qkvw  = (const float*)d_in[1];
  const float* projw = (const float*)d_in[2];
  const float* projb = (const float*)d_in[3];
  const float* btab  = (const float*)d_in[4];
  float* out = (float*)d_out;

  if (ws_size >= 131072) {
    unsigned short* wsb = (unsigned short*)d_ws;
    prep_weights<<<64, 256, 0, stream>>>(qkvw, projw, wsb);
    swin_fused<true><<<8192, 256, 0, stream>>>(x, qkvw, projw, projb, btab, wsb, out);
  } else {
    swin_fused<false><<<8192, 256, 0, stream>>>(x, qkvw, projw, projb, btab, nullptr, out);
  }
}

// Round 4
// 415.751 us; speedup vs baseline: 1.3023x; 1.3023x over previous
//
#include <hip/hip_runtime.h>

typedef __attribute__((ext_vector_type(8))) short short8;
typedef __attribute__((ext_vector_type(4))) unsigned short ushort4v;
typedef __attribute__((ext_vector_type(4))) float f32x4;

#define SCALE_F 0.17677669529663687f  // 1/sqrt(32)
// swizzle: uses both token-col (t&7) and token-row (t>>3) bits
#define SW(t) ((((t) ^ ((t) >> 3)) & 7) << 4)

__device__ __forceinline__ unsigned short f2bf(float f){
  unsigned u = __builtin_bit_cast(unsigned, f);
  u += 0x7fffu + ((u >> 16) & 1u);          // RNE
  return (unsigned short)(u >> 16);
}
__device__ __forceinline__ float bf2f(unsigned short h){
  unsigned u = ((unsigned)h) << 16;
  return __builtin_bit_cast(float, u);
}
__device__ __forceinline__ unsigned cvtpk(float a, float b){
  unsigned w;
  asm("v_cvt_pk_bf16_f32 %0, %1, %2" : "=v"(w) : "v"(a), "v"(b));
  return w;
}
__device__ __forceinline__ void st_pk4(void* p, f32x4 a){
  uint2 u; u.x = cvtpk(a[0], a[1]); u.y = cvtpk(a[2], a[3]);
  *(uint2*)p = u;
}

// ---------------------------------------------------------------------------
// LDS map (64 KiB total -> 2 blocks/CU)  [identical to the proven R1 kernel]:
//   [    0,16384) : ph1-2: x window bf16 [t=64][c=128] swizzled (rowstride 256B)
//                   ph3  : S bf16 [64][64] (0..8K), P bf16 [64][64] (8K..16K)
//   [16384,32768) : q bf16 [t=64][c=128] swz     -> ph4+: attn-out bf16 [t][c]
//   [32768,49152) : k bf16 [t=64][c=128] swz
//   [49152,65536) : v^T bf16 [c=128][t=64] swz (rowstride 128B)
// Swizzle: byte_col ^ SW(row) -- consistent on every read & write.
// ---------------------------------------------------------------------------

template<bool WSB>
__global__ void __launch_bounds__(256, 2)
swin_fused(const float* __restrict__ x, const float* __restrict__ qkvw_f,
           const float* __restrict__ projw_f, const float* __restrict__ projb,
           const float* __restrict__ btab, const unsigned short* __restrict__ wbf,
           float* __restrict__ out)
{
  __shared__ __align__(16) unsigned char sm[65536];
  const int tid  = threadIdx.x;
  const int lane = tid & 63, wv = tid >> 6;
  const int lr = lane & 15, lg = lane >> 4;

  // XCD-aware swizzle: 8192 blocks, 8 XCDs -> each XCD one batch plane
  const int bid = blockIdx.x;
  const int sw  = ((bid & 7) << 10) | (bid >> 3);
  const int b   = sw >> 10;
  const int wh  = (sw >> 5) & 31, ww = sw & 31;
  const int hb  = wh * 8 + 4, wb = ww * 8 + 4;   // roll(-4): shifted -> source
  const bool h31 = (wh == 31), w31 = (ww == 31);

  // ---- Hoisted proj weights + bias (used only in phase 5; issue early so
  //      the L2 latency hides under the whole kernel) ----
  short8 BwH[2][4];
  float pbH[2];
  #pragma unroll
  for (int ntl = 0; ntl < 2; ++ntl) {
    const int o = (wv + 4 * ntl) * 16 + lr;
    pbH[ntl] = projb[o];
    #pragma unroll
    for (int kk = 0; kk < 4; ++kk) {
      const int off = o * 128 + kk * 32 + 8 * lg;
      if constexpr (WSB) {
        BwH[ntl][kk] = *(const short8*)(wbf + 49152 + off);
      } else {
        const float* p = projw_f + off;
        short8 r;
        #pragma unroll
        for (int e = 0; e < 8; ++e) r[e] = (short)f2bf(p[e]);
        BwH[ntl][kk] = r;
      }
    }
  }

  // ---- Phase 1: load x window (float4, roll -4,-4) -> bf16 LDS swizzled ----
  {
    #pragma unroll
    for (int it = 0; it < 8; ++it) {
      const int f = tid + 256 * it;          // 0..2047 float4-units
      const int c    = f >> 4;               // channel
      const int rr   = (f >> 1) & 7;         // window row
      const int half = f & 1;                // which float4 of the row
      const int gh = (hb + rr) & 255;
      const int gw = (wb + 4 * half) & 255;  // 16B aligned, no intra-wrap
      const f32x4 v = *(const f32x4*)(x + (((b * 128 + c) << 16) + (gh << 8) + gw));
      const int t0 = rr * 8 + 4 * half;
      #pragma unroll
      for (int e = 0; e < 4; ++e) {
        const int t = t0 + e;
        *(unsigned short*)(sm + t * 256 + ((2 * c) ^ SW(t))) = f2bf(v[e]);
      }
    }
  }
  __syncthreads();

  // ---- Phase 2: QKV = W * x^T  (D[o][t]; M=o 24 tiles, N=t 4, K=c 4) ----
  {
    short8 Bf[16];                      // x^T fragments, reused by all o-tiles
    #pragma unroll
    for (int nt = 0; nt < 4; ++nt)
      #pragma unroll
      for (int kk = 0; kk < 4; ++kk) {
        const int t = nt * 16 + lr;
        Bf[nt * 4 + kk] = *(short8*)(sm + t * 256 + ((64 * kk + 16 * lg) ^ SW(t)));
      }
    #pragma unroll
    for (int jj = 0; jj < 6; ++jj) {
      const int mt = wv + 4 * jj;       // wave gets o-tiles {wv, wv+4, ...}
      const int orow = mt * 16 + lr;
      short8 Af[4];
      #pragma unroll
      for (int kk = 0; kk < 4; ++kk) {
        const int off = orow * 128 + kk * 32 + 8 * lg;
        if constexpr (WSB) {
          Af[kk] = *(const short8*)(wbf + off);
        } else {
          const float* p = qkvw_f + off;
          short8 r;
          #pragma unroll
          for (int e = 0; e < 8; ++e) r[e] = (short)f2bf(p[e]);
          Af[kk] = r;
        }
      }
      f32x4 acc[4];
      #pragma unroll
      for (int nt = 0; nt < 4; ++nt) {
        acc[nt] = (f32x4)(0.f);
        #pragma unroll
        for (int kk = 0; kk < 4; ++kk)
          acc[nt] = __builtin_amdgcn_mfma_f32_16x16x32_bf16(Af[kk], Bf[nt * 4 + kk], acc[nt], 0, 0, 0);
      }
      // epilogue: D rows o = mt*16 + 4*lg + r, col t = nt*16+lr
      if (mt < 16) {                    // q or k: pack 4 consecutive channels
        const int base = (mt < 8) ? 16384 : 32768;
        const int c0 = ((mt & 7) * 16) + 4 * lg;
        #pragma unroll
        for (int nt = 0; nt < 4; ++nt) {
          const int t = nt * 16 + lr;
          ushort4v pk;
          #pragma unroll
          for (int r = 0; r < 4; ++r) pk[r] = f2bf(acc[nt][r]);
          *(ushort4v*)(sm + base + t * 256 + ((2 * c0) ^ SW(t))) = pk;
        }
      } else {                          // v: store transposed vT[c][t]
        const int c0 = (mt - 16) * 16 + 4 * lg;
        #pragma unroll
        for (int nt = 0; nt < 4; ++nt) {
          const int t = nt * 16 + lr;
          #pragma unroll
          for (int r = 0; r < 4; ++r) {
            const int c = c0 + r;
            *(unsigned short*)(sm + 49152 + c * 128 + ((2 * t) ^ SW(c))) = f2bf(acc[nt][r]);
          }
        }
      }
    }
  }
  __syncthreads();

  // Per-thread constants for attention epilogues
  const int ktc = wv * 16 + lr;              // key column owned in QK
  const int ki = ktc >> 3, kj = ktc & 7;
  int boff[4][4];
  #pragma unroll
  for (int mt = 0; mt < 4; ++mt)
    #pragma unroll
    for (int r = 0; r < 4; ++r) {
      const int qrow = mt * 16 + 4 * lg + r;
      boff[mt][r] = (((qrow >> 3) - ki + 7) * 15 + ((qrow & 7) - kj + 7)) * 4;
    }

  f32x4 accpv[8];
  #pragma unroll
  for (int z = 0; z < 8; ++z) accpv[z] = (f32x4)(0.f);

  #pragma unroll 1
  for (int h = 0; h < 4; ++h) {
    // ---- QK^T (+bias +mask) -> S ----
    {
      const int cb = 64 * h + 16 * lg;             // byte col into head-h slice
      const short8 kb = *(short8*)(sm + 32768 + ktc * 256 + (cb ^ SW(ktc)));
      #pragma unroll
      for (int mt = 0; mt < 4; ++mt) {
        const int q = mt * 16 + lr;
        const short8 qa = *(short8*)(sm + 16384 + q * 256 + (cb ^ SW(q)));
        f32x4 sacc = __builtin_amdgcn_mfma_f32_16x16x32_bf16(qa, kb, (f32x4)(0.f), 0, 0, 0);
        #pragma unroll
        for (int r = 0; r < 4; ++r) {
          const int qrow = mt * 16 + 4 * lg + r;
          float s = sacc[r] * SCALE_F;
          s += btab[boff[mt][r] + h];
          if (h31 | w31) {
            const int qi = qrow >> 3, qj = qrow & 7;
            const bool bad = (h31 && ((qi >= 4) != (ki >= 4))) ||
                             (w31 && ((qj >= 4) != (kj >= 4)));
            s += bad ? -100.f : 0.f;
          }
          *(unsigned short*)(sm + qrow * 128 + ((2 * ktc) ^ SW(qrow))) = f2bf(s);
        }
      }
    }
    __syncthreads();
    // ---- softmax: 4 lanes per row, S -> P (disjoint halves of [0,16K)) ----
    {
      const int srow = tid >> 2, sq = tid & 3;
      const int swz = SW(srow);
      const short8 s0 = *(short8*)(sm + srow * 128 + ((sq * 32) ^ swz));
      const short8 s1 = *(short8*)(sm + srow * 128 + ((sq * 32 + 16) ^ swz));
      float v[16];
      #pragma unroll
      for (int e = 0; e < 8; ++e) { v[e] = bf2f((unsigned short)s0[e]); v[e + 8] = bf2f((unsigned short)s1[e]); }
      float mx = v[0];
      #pragma unroll
      for (int e = 1; e < 16; ++e) mx = fmaxf(mx, v[e]);
      mx = fmaxf(mx, __shfl_xor(mx, 1));
      mx = fmaxf(mx, __shfl_xor(mx, 2));
      float sum = 0.f;
      #pragma unroll
      for (int e = 0; e < 16; ++e) { v[e] = __expf(v[e] - mx); sum += v[e]; }
      sum += __shfl_xor(sum, 1);
      sum += __shfl_xor(sum, 2);
      const float inv = 1.f / sum;
      short8 p0, p1;
      #pragma unroll
      for (int e = 0; e < 8; ++e) { p0[e] = (short)f2bf(v[e] * inv); p1[e] = (short)f2bf(v[e + 8] * inv); }
      *(short8*)(sm + 8192 + srow * 128 + ((sq * 32) ^ swz)) = p0;
      *(short8*)(sm + 8192 + srow * 128 + ((sq * 32 + 16) ^ swz)) = p1;
    }
    __syncthreads();
    // ---- PV: wave owns q rows [16wv,16wv+16); accumulate over heads ----
    {
      const int q = wv * 16 + lr;
      const short8 pa0 = *(short8*)(sm + 8192 + q * 128 + ((16 * lg) ^ SW(q)));
      const short8 pa1 = *(short8*)(sm + 8192 + q * 128 + ((64 + 16 * lg) ^ SW(q)));
      #pragma unroll
      for (int nd = 0; nd < 2; ++nd) {
        const int c = h * 32 + nd * 16 + lr;       // vT row = head channel
        const short8 vb0 = *(short8*)(sm + 49152 + c * 128 + ((16 * lg) ^ SW(c)));
        const short8 vb1 = *(short8*)(sm + 49152 + c * 128 + ((64 + 16 * lg) ^ SW(c)));
        f32x4 a = accpv[h * 2 + nd];
        a = __builtin_amdgcn_mfma_f32_16x16x32_bf16(pa0, vb0, a, 0, 0, 0);
        a = __builtin_amdgcn_mfma_f32_16x16x32_bf16(pa1, vb1, a, 0, 0, 0);
        accpv[h * 2 + nd] = a;
      }
    }
    // no barrier: next QK writes S (0..8K) while laggards read P (8K..16K)
  }

  // ---- Phase 4: attn-out -> LDS (overlays q region; q fully consumed) ----
  {
    #pragma unroll
    for (int h = 0; h < 4; ++h)
      #pragma unroll
      for (int nd = 0; nd < 2; ++nd) {
        const int c = h * 32 + nd * 16 + lr;
        const f32x4 a = accpv[h * 2 + nd];
        #pragma unroll
        for (int r = 0; r < 4; ++r) {
          const int t = wv * 16 + 4 * lg + r;
          *(unsigned short*)(sm + 16384 + t * 256 + ((2 * c) ^ SW(t))) = f2bf(a[r]);
        }
      }
  }
  __syncthreads();

  // ---- Phase 5: proj (D[t][o]) + bias + store with roll(+4,+4) ----
  {
    short8 Aa[16];
    #pragma unroll
    for (int mt = 0; mt < 4; ++mt)
      #pragma unroll
      for (int kk = 0; kk < 4; ++kk) {
        const int t = mt * 16 + lr;
        Aa[mt * 4 + kk] = *(short8*)(sm + 16384 + t * 256 + ((64 * kk + 16 * lg) ^ SW(t)));
      }
    #pragma unroll
    for (int ntl = 0; ntl < 2; ++ntl) {
      const int o = (wv + 4 * ntl) * 16 + lr;
      const float pb = pbH[ntl];
      #pragma unroll
      for (int mt = 0; mt < 4; ++mt) {
        f32x4 acc = (f32x4)(0.f);
        #pragma unroll
        for (int kk = 0; kk < 4; ++kk)
          acc = __builtin_amdgcn_mfma_f32_16x16x32_bf16(Aa[mt * 4 + kk], BwH[ntl][kk], acc, 0, 0, 0);
        const int t0 = mt * 16 + 4 * lg;       // 4 consecutive tokens, same row
        const int gh = (hb + (t0 >> 3)) & 255;
        const int gw0 = (wb + (t0 & 7)) & 255; // mult of 4 -> aligned, no wrap
        f32x4 ov;
        ov[0] = acc[0] + pb; ov[1] = acc[1] + pb; ov[2] = acc[2] + pb; ov[3] = acc[3] + pb;
        *(f32x4*)(out + (((b * 128 + o) << 16) + (gh << 8) + gw0)) = ov;
      }
    }
  }
}

// One-time (per launch) weight fp32 -> bf16 into workspace.
__global__ void prep_weights(const float* __restrict__ qw, const float* __restrict__ pw,
                             unsigned short* __restrict__ wsb)
{
  const int i = blockIdx.x * 256 + threadIdx.x;
  const int idx = i * 4;                        // 65536 elements total
  const float* src = (idx < 49152) ? (qw + idx) : (pw + (idx - 49152));
  f32x4 v = *(const f32x4*)src;
  ushort4v o;
  #pragma unroll
  for (int e = 0; e < 4; ++e) o[e] = f2bf(v[e]);
  *(ushort4v*)(wsb + idx) = o;
}

extern "C" void kernel_launch(void* const* d_in, const int* in_sizes, int n_in,
                              void* d_out, int out_size, void* d_ws, size_t ws_size,
                              hipStream_t stream) {
  const float* x     = (const float*)d_in[0];
  const float* qkvw  = (const float*)d_in[1];
  const float* projw = (const float*)d_in[2];
  const float* projb = (const float*)d_in[3];
  const float* btab  = (const float*)d_in[4];
  float* out = (float*)d_out;

  if (ws_size >= 131072) {
    unsigned short* wsb = (unsigned short*)d_ws;
    prep_weights<<<64, 256, 0, stream>>>(qkvw, projw, wsb);
    swin_fused<true><<<8192, 256, 0, stream>>>(x, qkvw, projw, projb, btab, wsb, out);
  } else {
    swin_fused<false><<<8192, 256, 0, stream>>>(x, qkvw, projw, projb, btab, nullptr, out);
  }
}